// Round 1
// baseline (57.600 us; speedup 1.0000x reference)
//
#include <hip/hip_runtime.h>

namespace {

constexpr int kB = 8, kN = 256, kF = 128, kH = 128, kO = 64;
constexpr int kR = 8;            // rows per block
constexpr int kTPB = 256;        // 4 waves
constexpr int kOut0 = kB * kN * kO;   // 131072 floats: "out" part; h_new follows

__device__ __forceinline__ float waveReduceAdd(float v) {
    v += __shfl_xor(v, 1);
    v += __shfl_xor(v, 2);
    v += __shfl_xor(v, 4);
    v += __shfl_xor(v, 8);
    v += __shfl_xor(v, 16);
    v += __shfl_xor(v, 32);
    return v;
}

__device__ __forceinline__ float dot4(float4 a, float4 b) {
    return a.x * b.x + a.y * b.y + a.z * b.z + a.w * b.w;
}

__global__ __launch_bounds__(kTPB) void weak_tie_fused(
    const float* __restrict__ lx, const float* __restrict__ gx,
    const float* __restrict__ mask, const int* __restrict__ key_idx,
    const float* __restrict__ hstate,
    const float* __restrict__ fc_w, const float* __restrict__ fc_b,
    const float* __restrict__ ln_g, const float* __restrict__ ln_b,
    const float* __restrict__ w_ih, const float* __restrict__ w_hh,
    const float* __restrict__ b_ih, const float* __restrict__ b_hh,
    const float* __restrict__ out_w, const float* __restrict__ out_b,
    float* __restrict__ out)
{
    __shared__ float maskbuf[kR][kN];       // 8 KB
    __shared__ float cmb[kR][3 * kF];       // 12 KB  [local | weak | key]
    __shared__ float keybuf[kF];
    __shared__ float hfbuf[kR][kH];         // hidden_state rows
    __shared__ float scratch[kR][kH];       // partial-sum exchange
    __shared__ float hbuf[kR][kH];          // pre-LN h
    __shared__ float xbuf[kR][kH];          // post-ReLU x
    __shared__ float ghbuf[kR][3][kH];      // gh gate pre-activations
    __shared__ float hnbuf[kR][kH];         // h_new
    __shared__ float denomInv[kR];

    const int tid  = threadIdx.x;
    const int b    = blockIdx.x >> 5;       // 32 tiles per batch (N/R)
    const int row0 = (blockIdx.x & 31) * kR;
    const int f    = tid & 127;             // output-feature / f index
    const int g    = tid >> 7;              // half id: 0 or 1
    const int lane = tid & 63;
    const int wv   = tid >> 6;              // wave 0..3

    // ---- stage inputs ----
    const float* mrow = mask + ((size_t)b * kN + row0) * kN;
    #pragma unroll
    for (int it = 0; it < kR * kN / kTPB; ++it) {
        int idx = it * kTPB + tid;
        ((float*)maskbuf)[idx] = mrow[idx];
    }
    const float* lrow = lx + ((size_t)b * kN + row0) * kF;
    #pragma unroll
    for (int it = 0; it < kR * kF / kTPB; ++it) {
        int idx = it * kTPB + tid;
        cmb[idx >> 7][idx & 127] = lrow[idx];
    }
    const float* hrow = hstate + ((size_t)b * kN + row0) * kH;
    #pragma unroll
    for (int it = 0; it < kR * kH / kTPB; ++it) {
        int idx = it * kTPB + tid;
        hfbuf[idx >> 7][idx & 127] = hrow[idx];
    }
    const int ki = key_idx[b];
    if (tid < kF) keybuf[tid] = gx[((size_t)b * kN + ki) * kF + tid];
    __syncthreads();

    // ---- denom per row (wave wv handles rows wv, wv+4) ----
    #pragma unroll
    for (int rr = 0; rr < 2; ++rr) {
        int r = wv + rr * 4;
        float s = maskbuf[r][lane] + maskbuf[r][lane + 64] +
                  maskbuf[r][lane + 128] + maskbuf[r][lane + 192];
        s = waveReduceAdd(s);
        if (lane == 0) denomInv[r] = 1.0f / (s + 1e-6f);
    }
    __syncthreads();

    // ---- weak = (mask @ gx) / denom ; half g covers j in [g*128, g*128+128) ----
    {
        float acc[kR];
        #pragma unroll
        for (int r = 0; r < kR; ++r) acc[r] = 0.f;
        const float* gbase = gx + ((size_t)b * kN + g * 128) * kF + f;
        for (int j = 0; j < 128; ++j) {
            float gv = gbase[(size_t)j * kF];           // coalesced across f
            #pragma unroll
            for (int r = 0; r < kR; ++r)
                acc[r] += maskbuf[r][g * 128 + j] * gv; // LDS broadcast
        }
        if (g == 1) {
            #pragma unroll
            for (int r = 0; r < kR; ++r) scratch[r][f] = acc[r];
            #pragma unroll
            for (int r = 0; r < kR; ++r) cmb[r][2 * kF + f] = keybuf[f];
        }
        __syncthreads();
        if (g == 0) {
            #pragma unroll
            for (int r = 0; r < kR; ++r)
                cmb[r][kF + f] = (acc[r] + scratch[r][f]) * denomInv[r];
        }
        __syncthreads();
    }

    // ---- h = combined @ fc_w.T + fc_b ; half g covers k in [g*192, g*192+192) ----
    {
        float acc[kR];
        #pragma unroll
        for (int r = 0; r < kR; ++r) acc[r] = 0.f;
        const float* wrowp = fc_w + (size_t)f * 384 + g * 192;
        for (int kk = 0; kk < 192; kk += 4) {
            float4 w4 = *(const float4*)(wrowp + kk);
            #pragma unroll
            for (int r = 0; r < kR; ++r) {
                float4 c4 = *(const float4*)&cmb[r][g * 192 + kk];
                acc[r] += dot4(w4, c4);
            }
        }
        if (g == 1) {
            #pragma unroll
            for (int r = 0; r < kR; ++r) scratch[r][f] = acc[r];
        }
        __syncthreads();
        if (g == 0) {
            float bias = fc_b[f];
            #pragma unroll
            for (int r = 0; r < kR; ++r)
                hbuf[r][f] = acc[r] + scratch[r][f] + bias;
        }
        __syncthreads();
    }

    // ---- LayerNorm + ReLU (wave wv handles rows wv, wv+4) ----
    {
        float g0 = ln_g[lane], b0 = ln_b[lane];
        float g1 = ln_g[lane + 64], b1 = ln_b[lane + 64];
        #pragma unroll
        for (int rr = 0; rr < 2; ++rr) {
            int r = wv + rr * 4;
            float v0 = hbuf[r][lane], v1 = hbuf[r][lane + 64];
            float s  = waveReduceAdd(v0 + v1);
            float ss = waveReduceAdd(v0 * v0 + v1 * v1);
            float mu   = s * (1.0f / 128.0f);
            float var  = ss * (1.0f / 128.0f) - mu * mu;
            float rstd = rsqrtf(var + 1e-5f);
            xbuf[r][lane]      = fmaxf((v0 - mu) * rstd * g0 + b0, 0.f);
            xbuf[r][lane + 64] = fmaxf((v1 - mu) * rstd * g1 + b1, 0.f);
        }
    }
    __syncthreads();

    // ---- GRU gate matmuls: g==0 -> gi (from xbuf), g==1 -> gh (from hfbuf) ----
    float aR[kR], aZ[kR], aN[kR];
    #pragma unroll
    for (int r = 0; r < kR; ++r) { aR[r] = 0.f; aZ[r] = 0.f; aN[r] = 0.f; }
    {
        const float* wsrc = (g == 0) ? w_ih : w_hh;
        const float* w0 = wsrc + (size_t)f * kH;
        const float* w1 = wsrc + (size_t)(f + 128) * kH;
        const float* w2 = wsrc + (size_t)(f + 256) * kH;
        const float (*abuf)[kH] = (g == 0) ? xbuf : hfbuf;
        for (int kk = 0; kk < kH; kk += 4) {
            float4 x0 = *(const float4*)(w0 + kk);
            float4 x1 = *(const float4*)(w1 + kk);
            float4 x2 = *(const float4*)(w2 + kk);
            #pragma unroll
            for (int r = 0; r < kR; ++r) {
                float4 a4 = *(const float4*)&abuf[r][kk];  // LDS broadcast
                aR[r] += dot4(x0, a4);
                aZ[r] += dot4(x1, a4);
                aN[r] += dot4(x2, a4);
            }
        }
    }
    if (g == 1) {
        #pragma unroll
        for (int r = 0; r < kR; ++r) {
            ghbuf[r][0][f] = aR[r];
            ghbuf[r][1][f] = aZ[r];
            ghbuf[r][2][f] = aN[r];
        }
    }
    __syncthreads();
    if (g == 0) {
        float bi_r = b_ih[f], bi_z = b_ih[f + 128], bi_n = b_ih[f + 256];
        float bh_r = b_hh[f], bh_z = b_hh[f + 128], bh_n = b_hh[f + 256];
        #pragma unroll
        for (int r = 0; r < kR; ++r) {
            float ir = aR[r] + bi_r, iz = aZ[r] + bi_z, inn = aN[r] + bi_n;
            float hr = ghbuf[r][0][f] + bh_r;
            float hz = ghbuf[r][1][f] + bh_z;
            float hn = ghbuf[r][2][f] + bh_n;
            float rg = 1.0f / (1.0f + __expf(-(ir + hr)));
            float zg = 1.0f / (1.0f + __expf(-(iz + hz)));
            float ng = tanhf(inn + rg * hn);
            float hprev = hfbuf[r][f];
            float hnew = (1.0f - zg) * ng + zg * hprev;
            hnbuf[r][f] = hnew;
            out[kOut0 + ((size_t)(b * kN + row0 + r)) * kH + f] = hnew;
        }
    }
    __syncthreads();

    // ---- out = h_new @ out_w.T + out_b (wave wv does rows wv, wv+4) ----
    {
        int oo = tid & 63;
        float ob = out_b[oo];
        const float* wrowp = out_w + (size_t)oo * kH;
        #pragma unroll
        for (int rr = 0; rr < 2; ++rr) {
            int r = wv + rr * 4;
            float acc = 0.f;
            for (int kk = 0; kk < kH; kk += 4) {
                float4 w4 = *(const float4*)(wrowp + kk);
                float4 h4 = *(const float4*)&hnbuf[r][kk]; // LDS broadcast
                acc += dot4(w4, h4);
            }
            out[((size_t)(b * kN + row0 + r)) * kO + oo] = acc + ob;
        }
    }
}

} // namespace

extern "C" void kernel_launch(void* const* d_in, const int* in_sizes, int n_in,
                              void* d_out, int out_size, void* d_ws, size_t ws_size,
                              hipStream_t stream) {
    const float* lx      = (const float*)d_in[0];
    const float* gx      = (const float*)d_in[1];
    const float* mask    = (const float*)d_in[2];
    const int*   key_idx = (const int*)  d_in[3];
    const float* hs      = (const float*)d_in[4];
    const float* fc_w    = (const float*)d_in[5];
    const float* fc_b    = (const float*)d_in[6];
    const float* ln_g    = (const float*)d_in[7];
    const float* ln_b    = (const float*)d_in[8];
    const float* w_ih    = (const float*)d_in[9];
    const float* w_hh    = (const float*)d_in[10];
    const float* b_ih    = (const float*)d_in[11];
    const float* b_hh    = (const float*)d_in[12];
    const float* out_w   = (const float*)d_in[13];
    const float* out_b   = (const float*)d_in[14];
    float* out = (float*)d_out;

    dim3 grid(kB * kN / kR);   // 256 blocks
    dim3 block(kTPB);          // 256 threads
    hipLaunchKernelGGL(weak_tie_fused, grid, block, 0, stream,
                       lx, gx, mask, key_idx, hs,
                       fc_w, fc_b, ln_g, ln_b,
                       w_ih, w_hh, b_ih, b_hh,
                       out_w, out_b, out);
}

// Round 3
// 48.588 us; speedup vs baseline: 1.1855x; 1.1855x over previous
//
#include <hip/hip_runtime.h>

namespace {

constexpr int kB = 8, kN = 256, kF = 128, kH = 128, kO = 64;
constexpr int kR = 8;              // rows per block
constexpr int kTPB = 1024;         // 16 waves
constexpr int kOut0 = kB * kN * kO;

// shared-memory layout (float offsets), unions by liveness:
//   [0..2048)      maskbuf[8][256]   (staging..weak)   -> hbuf[8][128] @0, hnbuf[8][128] @1024
//   [2048..5120)   cmb[8][384]
//   [5120..6144)   hfbuf[8][128]
//   [6144..7168)   xbuf[8][128]
//   [7168..15360)  union: scr[7][8][128] (weak/FC reduce) | gate[6][8][128] + part[2][8][128] (GRU)
constexpr int SM_HBUF  = 0;
constexpr int SM_HNBUF = 1024;
constexpr int SM_MASK  = 0;
constexpr int SM_CMB   = 2048;
constexpr int SM_HF    = 5120;
constexpr int SM_XB    = 6144;
constexpr int SM_SCR   = 7168;
constexpr int SM_GATE  = 7168;
constexpr int SM_PART  = 7168 + 6144;
constexpr int SM_TOTAL = 7168 + 8192;   // 15360 floats = 60 KB

__device__ __forceinline__ float waveReduceAdd(float v) {
    v += __shfl_xor(v, 1);
    v += __shfl_xor(v, 2);
    v += __shfl_xor(v, 4);
    v += __shfl_xor(v, 8);
    v += __shfl_xor(v, 16);
    v += __shfl_xor(v, 32);
    return v;
}

__device__ __forceinline__ float dot4(float4 a, float4 b) {
    return a.x * b.x + a.y * b.y + a.z * b.z + a.w * b.w;
}

__global__ __launch_bounds__(kTPB, 4) void weak_tie_fused(
    const float* __restrict__ lx, const float* __restrict__ gx,
    const float* __restrict__ mask, const int* __restrict__ key_idx,
    const float* __restrict__ hstate,
    const float* __restrict__ fc_w, const float* __restrict__ fc_b,
    const float* __restrict__ ln_g, const float* __restrict__ ln_b,
    const float* __restrict__ w_ih, const float* __restrict__ w_hh,
    const float* __restrict__ b_ih, const float* __restrict__ b_hh,
    const float* __restrict__ out_w, const float* __restrict__ out_b,
    float* __restrict__ out)
{
    __shared__ __align__(16) float sm[SM_TOTAL];
    __shared__ float denomInv[kR];

    const int tid  = threadIdx.x;
    const int b    = blockIdx.x >> 5;        // 32 row-tiles per batch
    const int row0 = (blockIdx.x & 31) * kR;
    const int f    = tid & 127;
    const int q    = tid >> 7;               // 0..7
    const int lane = tid & 63;
    const int wv   = tid >> 6;               // 0..15

    float* maskb = sm + SM_MASK;
    float* cmb   = sm + SM_CMB;
    float* hf    = sm + SM_HF;
    float* xb    = sm + SM_XB;
    float* hb    = sm + SM_HBUF;
    float* hnb   = sm + SM_HNBUF;
    float* scr   = sm + SM_SCR;
    float* gate  = sm + SM_GATE;
    float* part  = sm + SM_PART;

    // ---------------- staging ----------------
    {
        const float* mrow = mask + ((size_t)b * kN + row0) * kN;
        #pragma unroll
        for (int it = 0; it < kR * kN / kTPB; ++it)   // 2 iters
            maskb[it * kTPB + tid] = mrow[it * kTPB + tid];
        const float* lrow = lx + ((size_t)b * kN + row0) * kF;
        cmb[(tid >> 7) * 384 + (tid & 127)] = lrow[tid];       // local_x -> cmb[:,0:128)
        const float* hrow = hstate + ((size_t)b * kN + row0) * kH;
        hf[tid] = hrow[tid];
        if (tid < kF) {
            const int ki = key_idx[b];
            float kv = gx[((size_t)b * kN + ki) * kF + tid];
            #pragma unroll
            for (int r = 0; r < kR; ++r) cmb[r * 384 + 256 + tid] = kv;  // key -> cmb[:,256:384)
        }
    }
    __syncthreads();

    // denom (waves 0..7, one row each) — consumed after the weak-partial barrier
    if (wv < 8) {
        int r = wv;
        float s = maskb[r * 256 + lane]       + maskb[r * 256 + lane + 64] +
                  maskb[r * 256 + lane + 128] + maskb[r * 256 + lane + 192];
        s = waveReduceAdd(s);
        if (lane == 0) denomInv[r] = 1.0f / (s + 1e-6f);
    }

    // ---------------- weak = (mask @ gx) / denom ; q-group owns j in [q*32, q*32+32) ----------------
    {
        float acc[kR];
        #pragma unroll
        for (int r = 0; r < kR; ++r) acc[r] = 0.f;
        const float* gb = gx + ((size_t)b * kN + q * 32) * kF + f;
        for (int j = 0; j < 32; ++j) {
            float gv = gb[(size_t)j * kF];          // coalesced across f
            #pragma unroll
            for (int r = 0; r < kR; ++r)
                acc[r] += maskb[r * 256 + q * 32 + j] * gv;   // LDS broadcast
        }
        if (q > 0) {
            #pragma unroll
            for (int r = 0; r < kR; ++r) scr[((q - 1) * kR + r) * 128 + f] = acc[r];
        }
        __syncthreads();
        if (q == 0) {
            #pragma unroll
            for (int r = 0; r < kR; ++r) {
                float a = acc[r];
                #pragma unroll
                for (int i = 0; i < 7; ++i) a += scr[(i * kR + r) * 128 + f];
                cmb[r * 384 + 128 + f] = a * denomInv[r];     // weak -> cmb[:,128:256)
            }
        }
        __syncthreads();
    }

    // ---------------- h = combined @ fc_w.T + fc_b ; q-group owns k in [q*48, q*48+48) ----------------
    {
        float acc[kR];
        #pragma unroll
        for (int r = 0; r < kR; ++r) acc[r] = 0.f;
        const float* wr = fc_w + (size_t)f * 384 + q * 48;
        for (int kk = 0; kk < 48; kk += 4) {
            float4 w4 = *(const float4*)(wr + kk);
            #pragma unroll
            for (int r = 0; r < kR; ++r) {
                float4 c4 = *(const float4*)&cmb[r * 384 + q * 48 + kk];
                acc[r] += dot4(w4, c4);
            }
        }
        if (q > 0) {
            #pragma unroll
            for (int r = 0; r < kR; ++r) scr[((q - 1) * kR + r) * 128 + f] = acc[r];
        }
        __syncthreads();
        if (q == 0) {
            float bias = fc_b[f];
            #pragma unroll
            for (int r = 0; r < kR; ++r) {
                float a = acc[r] + bias;
                #pragma unroll
                for (int i = 0; i < 7; ++i) a += scr[(i * kR + r) * 128 + f];
                hb[r * 128 + f] = a;
            }
        }
        __syncthreads();
    }

    // ---------------- LayerNorm + ReLU (waves 0..7, one row each) ----------------
    if (wv < 8) {
        int r = wv;
        float g0 = ln_g[lane], b0 = ln_b[lane];
        float g1 = ln_g[lane + 64], b1 = ln_b[lane + 64];
        float v0 = hb[r * 128 + lane], v1 = hb[r * 128 + lane + 64];
        float s  = waveReduceAdd(v0 + v1);
        float ss = waveReduceAdd(v0 * v0 + v1 * v1);
        float mu   = s * (1.0f / 128.0f);
        float var  = ss * (1.0f / 128.0f) - mu * mu;
        float rstd = rsqrtf(var + 1e-5f);
        xb[r * 128 + lane]      = fmaxf((v0 - mu) * rstd * g0 + b0, 0.f);
        xb[r * 128 + lane + 64] = fmaxf((v1 - mu) * rstd * g1 + b1, 0.f);
    }
    __syncthreads();

    // ---------------- GRU gate matmuls (gate-stationary) ----------------
    // q: 0 i_r, 1 i_z, 2 h_r, 3 h_z (full K) ; 4/5 i_n K-halves ; 6/7 h_n K-halves
    // gate slots: 0 i_r, 1 i_z, 2 i_n, 3 h_r, 4 h_z, 5 h_n
    {
        float acc[kR];
        #pragma unroll
        for (int r = 0; r < kR; ++r) acc[r] = 0.f;
        const float* W; const float* A; int k0, klen;
        switch (q) {
            case 0:  W = w_ih + (size_t)f * 128;         A = xb; k0 = 0;  klen = 128; break;
            case 1:  W = w_ih + (size_t)(128 + f) * 128; A = xb; k0 = 0;  klen = 128; break;
            case 2:  W = w_hh + (size_t)f * 128;         A = hf; k0 = 0;  klen = 128; break;
            case 3:  W = w_hh + (size_t)(128 + f) * 128; A = hf; k0 = 0;  klen = 128; break;
            case 4:  W = w_ih + (size_t)(256 + f) * 128; A = xb; k0 = 0;  klen = 64;  break;
            case 5:  W = w_ih + (size_t)(256 + f) * 128; A = xb; k0 = 64; klen = 64;  break;
            case 6:  W = w_hh + (size_t)(256 + f) * 128; A = hf; k0 = 0;  klen = 64;  break;
            default: W = w_hh + (size_t)(256 + f) * 128; A = hf; k0 = 64; klen = 64;  break;
        }
        for (int kk = 0; kk < klen; kk += 4) {
            float4 w4 = *(const float4*)(W + k0 + kk);
            #pragma unroll
            for (int r = 0; r < kR; ++r) {
                float4 a4 = *(const float4*)&A[r * 128 + k0 + kk];  // LDS broadcast
                acc[r] += dot4(w4, a4);
            }
        }
        // gate slot mapping: q0->0 (i_r), q1->1 (i_z), q2->3 (h_r), q3->4 (h_z)
        if (q == 5) {
            #pragma unroll
            for (int r = 0; r < kR; ++r) part[(0 * kR + r) * 128 + f] = acc[r];
        }
        if (q == 7) {
            #pragma unroll
            for (int r = 0; r < kR; ++r) part[(1 * kR + r) * 128 + f] = acc[r];
        }
        if (q < 4) {
            const int slotmap[4] = {0, 1, 3, 4};
            int slot = slotmap[q];
            #pragma unroll
            for (int r = 0; r < kR; ++r) gate[(slot * kR + r) * 128 + f] = acc[r];
        }
        __syncthreads();
        if (q == 4) {
            #pragma unroll
            for (int r = 0; r < kR; ++r)
                gate[(2 * kR + r) * 128 + f] = acc[r] + part[(0 * kR + r) * 128 + f];
        }
        if (q == 6) {
            #pragma unroll
            for (int r = 0; r < kR; ++r)
                gate[(5 * kR + r) * 128 + f] = acc[r] + part[(1 * kR + r) * 128 + f];
        }
        __syncthreads();
    }

    // ---------------- gate combine: one thread per (row=q, f) ----------------
    {
        int r = q;
        float ir  = gate[(0 * kR + r) * 128 + f] + b_ih[f];
        float iz  = gate[(1 * kR + r) * 128 + f] + b_ih[128 + f];
        float inn = gate[(2 * kR + r) * 128 + f] + b_ih[256 + f];
        float hr  = gate[(3 * kR + r) * 128 + f] + b_hh[f];
        float hz  = gate[(4 * kR + r) * 128 + f] + b_hh[128 + f];
        float hn  = gate[(5 * kR + r) * 128 + f] + b_hh[256 + f];
        float rg = 1.0f / (1.0f + __expf(-(ir + hr)));
        float zg = 1.0f / (1.0f + __expf(-(iz + hz)));
        float ng = tanhf(inn + rg * hn);
        float hprev = hf[r * 128 + f];
        float hnew = (1.0f - zg) * ng + zg * hprev;
        hnb[r * 128 + f] = hnew;
        out[kOut0 + ((size_t)(b * kN + row0 + r)) * kH + f] = hnew;
    }
    __syncthreads();

    // ---------------- out = h_new @ out_w.T + out_b ----------------
    if (tid < 512) {
        int oo = tid & 63, r = tid >> 6;
        const float* wr = out_w + (size_t)oo * kH;
        float acc = 0.f;
        for (int kk = 0; kk < kH; kk += 4) {
            float4 w4 = *(const float4*)(wr + kk);
            float4 h4 = *(const float4*)&hnb[r * 128 + kk];   // LDS broadcast
            acc += dot4(w4, h4);
        }
        out[((size_t)(b * kN + row0 + r)) * kO + oo] = acc + out_b[oo];
    }
}

} // namespace

extern "C" void kernel_launch(void* const* d_in, const int* in_sizes, int n_in,
                              void* d_out, int out_size, void* d_ws, size_t ws_size,
                              hipStream_t stream) {
    const float* lx      = (const float*)d_in[0];
    const float* gx      = (const float*)d_in[1];
    const float* mask    = (const float*)d_in[2];
    const int*   key_idx = (const int*)  d_in[3];
    const float* hs      = (const float*)d_in[4];
    const float* fc_w    = (const float*)d_in[5];
    const float* fc_b    = (const float*)d_in[6];
    const float* ln_g    = (const float*)d_in[7];
    const float* ln_b    = (const float*)d_in[8];
    const float* w_ih    = (const float*)d_in[9];
    const float* w_hh    = (const float*)d_in[10];
    const float* b_ih    = (const float*)d_in[11];
    const float* b_hh    = (const float*)d_in[12];
    const float* out_w   = (const float*)d_in[13];
    const float* out_b   = (const float*)d_in[14];
    float* out = (float*)d_out;

    dim3 grid(kB * kN / kR);   // 256 blocks, 1 per CU
    dim3 block(kTPB);          // 1024 threads = 16 waves
    hipLaunchKernelGGL(weak_tie_fused, grid, block, 0, stream,
                       lx, gx, mask, key_idx, hs,
                       fc_w, fc_b, ln_g, ln_b,
                       w_ih, w_hh, b_ih, b_hh,
                       out_w, out_b, out);
}

// Round 4
// 27.448 us; speedup vs baseline: 2.0985x; 1.7702x over previous
//
#include <hip/hip_runtime.h>

namespace {

typedef unsigned short ushort_t;
typedef unsigned int uint_t;
typedef __attribute__((ext_vector_type(8))) short short8v;   // 8 bf16 (4 VGPRs)
typedef __attribute__((ext_vector_type(4))) float f32x4;     // MFMA accumulator

constexpr int kB = 8, kN = 256, kF = 128, kH = 128, kO = 64;
constexpr int kR = 8;              // real rows per block (padded to 16 for MFMA)
constexpr int kTPB = 1024;         // 16 waves
constexpr int kOut0 = kB * kN * kO;

union Frag {
    uint_t  u[4];
    short8v v;
};

__device__ __forceinline__ float waveReduceAdd(float v) {
    v += __shfl_xor(v, 1);
    v += __shfl_xor(v, 2);
    v += __shfl_xor(v, 4);
    v += __shfl_xor(v, 8);
    v += __shfl_xor(v, 16);
    v += __shfl_xor(v, 32);
    return v;
}

// fp32 -> bf16 (round-half-up) helpers
__device__ __forceinline__ ushort_t cvt1(float f) {
    return (ushort_t)((__float_as_uint(f) + 0x8000u) >> 16);
}
__device__ __forceinline__ uint_t pk(float f0, float f1) {
    uint_t b0 = __float_as_uint(f0) + 0x8000u;
    uint_t b1 = __float_as_uint(f1) + 0x8000u;
    return (b1 & 0xFFFF0000u) | (b0 >> 16);
}
__device__ __forceinline__ float b2f(ushort_t h) {
    return __uint_as_float(((uint_t)h) << 16);
}
// build B-frag from 8 consecutive fp32 at p (16B-aligned)
__device__ __forceinline__ void loadWFrag(const float* __restrict__ p, Frag& b) {
    float4 lo = *(const float4*)p;
    float4 hi = *(const float4*)(p + 4);
    b.u[0] = pk(lo.x, lo.y);
    b.u[1] = pk(lo.z, lo.w);
    b.u[2] = pk(hi.x, hi.y);
    b.u[3] = pk(hi.z, hi.w);
}

__global__ __launch_bounds__(kTPB, 4) void weak_tie_fused(
    const float* __restrict__ lx, const float* __restrict__ gx,
    const float* __restrict__ mask, const int* __restrict__ key_idx,
    const float* __restrict__ hstate,
    const float* __restrict__ fc_w, const float* __restrict__ fc_b,
    const float* __restrict__ ln_g, const float* __restrict__ ln_b,
    const float* __restrict__ w_ih, const float* __restrict__ w_hh,
    const float* __restrict__ b_ih, const float* __restrict__ b_hh,
    const float* __restrict__ out_w, const float* __restrict__ out_b,
    float* __restrict__ out)
{
    // bf16 activation tiles, 16 rows (8 real + 8 zero-pad), padded strides for banks
    __shared__ __align__(16) ushort_t maskb[16][264];   // mask rows (K=256)
    __shared__ __align__(16) ushort_t cmb[16][392];     // [local | weak | key] (K=384)
    __shared__ __align__(16) ushort_t hf16[16][136];
    __shared__ __align__(16) ushort_t xb16[16][136];
    __shared__ __align__(16) ushort_t hnb16[16][136];
    __shared__ __align__(16) float hf32[kR * kH];       // h_prev fp32 for gate combine
    __shared__ __align__(16) float hb[kR * kH];         // FC out pre-LN (no bias)
    __shared__ __align__(16) ushort_t ghb[kR][384];     // gh pre-activations (bf16)
    __shared__ __align__(16) ushort_t gib[kR][384];     // gi pre-activations (bf16)
    __shared__ float denomInv[kR];

    const int tid  = threadIdx.x;
    const int b    = blockIdx.x >> 5;
    const int row0 = (blockIdx.x & 31) * kR;
    const int lane = tid & 63;
    const int wv   = tid >> 6;            // wave 0..15
    const int arow = lane & 15;           // MFMA m/n index within tile
    const int kgrp = (lane >> 4) * 8;     // MFMA k sub-offset

    // ---------------- stage + zero pad rows ----------------
    {
        const int r = tid >> 7, c = tid & 127;
        const float* mrow = mask + ((size_t)b * kN + row0) * kN;
        maskb[r][c]       = cvt1(mrow[r * 256 + c]);
        maskb[r][c + 128] = cvt1(mrow[r * 256 + c + 128]);
        const float* lrow = lx + ((size_t)b * kN + row0) * kF;
        cmb[r][c] = cvt1(lrow[tid]);
        const int ki = key_idx[b];
        cmb[r][256 + c] = cvt1(gx[((size_t)b * kN + ki) * kF + c]);
        const float* hrow = hstate + ((size_t)b * kN + row0) * kH;
        float hv = hrow[tid];
        hf32[tid] = hv;
        hf16[r][c] = cvt1(hv);
        // zero pad rows 8..15 of all A-source buffers
        uint_t* z;
        z = (uint_t*)&maskb[8][0]; for (int i = tid; i < 8 * 264 / 2; i += kTPB) z[i] = 0;
        z = (uint_t*)&cmb[8][0];   for (int i = tid; i < 8 * 392 / 2; i += kTPB) z[i] = 0;
        z = (uint_t*)&hf16[8][0];  for (int i = tid; i < 8 * 136 / 2; i += kTPB) z[i] = 0;
        z = (uint_t*)&xb16[8][0];  for (int i = tid; i < 8 * 136 / 2; i += kTPB) z[i] = 0;
        z = (uint_t*)&hnb16[8][0]; for (int i = tid; i < 8 * 136 / 2; i += kTPB) z[i] = 0;
    }
    __syncthreads();

    // ---------------- denom (waves 0..7, one row each) ----------------
    if (wv < 8) {
        int r = wv;
        float s = b2f(maskb[r][lane])       + b2f(maskb[r][lane + 64]) +
                  b2f(maskb[r][lane + 128]) + b2f(maskb[r][lane + 192]);
        s = waveReduceAdd(s);
        if (lane == 0) denomInv[r] = 1.0f / (s + 1e-6f);
    }
    __syncthreads();

    // ---------------- phase 2: weak (waves 0-7)  ||  gh (waves 8-15) ----------------
    if (wv < 8) {
        const int n0 = 16 * wv;                       // weak feature tile
        const float* gxb = gx + (size_t)b * kN * kF;
        f32x4 acc = {0.f, 0.f, 0.f, 0.f};
        #pragma unroll
        for (int kf = 0; kf < 8; ++kf) {
            int k0 = kf * 32 + kgrp;                  // agent index j
            Frag a, bb;
            *(uint4*)a.u = *(const uint4*)&maskb[arow][k0];
            const float* gp = gxb + (size_t)k0 * kF + n0 + arow;
            bb.u[0] = pk(gp[0],   gp[128]);
            bb.u[1] = pk(gp[256], gp[384]);
            bb.u[2] = pk(gp[512], gp[640]);
            bb.u[3] = pk(gp[768], gp[896]);
            acc = __builtin_amdgcn_mfma_f32_16x16x32_bf16(a.v, bb.v, acc, 0, 0, 0);
        }
        #pragma unroll
        for (int j = 0; j < 4; ++j) {
            int row = (lane >> 4) * 4 + j;
            if (row < 8)
                cmb[row][128 + n0 + arow] = cvt1(acc[j] * denomInv[row]);
        }
    } else {
        const int w2 = wv - 8;
        Frag af[4];
        #pragma unroll
        for (int kf = 0; kf < 4; ++kf)
            *(uint4*)af[kf].u = *(const uint4*)&hf16[arow][kf * 32 + kgrp];
        #pragma unroll
        for (int t = 0; t < 3; ++t) {
            const int n0 = 16 * (w2 * 3 + t);         // gh output col tile (0..384)
            const float* wp = w_hh + (size_t)(n0 + arow) * kH + kgrp;
            f32x4 acc = {0.f, 0.f, 0.f, 0.f};
            #pragma unroll
            for (int kf = 0; kf < 4; ++kf) {
                Frag bb;
                loadWFrag(wp + kf * 32, bb);
                acc = __builtin_amdgcn_mfma_f32_16x16x32_bf16(af[kf].v, bb.v, acc, 0, 0, 0);
            }
            #pragma unroll
            for (int j = 0; j < 4; ++j) {
                int row = (lane >> 4) * 4 + j;
                if (row < 8) ghb[row][n0 + arow] = cvt1(acc[j]);
            }
        }
    }
    __syncthreads();

    // ---------------- phase 3: FC (waves 0-7)  ||  gi weight preload (waves 8-15) ----------------
    Frag bfr[12];    // held by waves 8-15 across barriers
    if (wv < 8) {
        const int n0 = 16 * wv;                       // FC output tile (0..128)
        const float* wp = fc_w + (size_t)(n0 + arow) * 384 + kgrp;
        f32x4 acc = {0.f, 0.f, 0.f, 0.f};
        #pragma unroll
        for (int kf = 0; kf < 12; ++kf) {
            Frag a, bb;
            *(uint4*)a.u = *(const uint4*)&cmb[arow][kf * 32 + kgrp];
            loadWFrag(wp + kf * 32, bb);
            acc = __builtin_amdgcn_mfma_f32_16x16x32_bf16(a.v, bb.v, acc, 0, 0, 0);
        }
        #pragma unroll
        for (int j = 0; j < 4; ++j) {
            int row = (lane >> 4) * 4 + j;
            if (row < 8) hb[row * 128 + n0 + arow] = acc[j];
        }
    } else {
        const int w2 = wv - 8;
        #pragma unroll
        for (int t = 0; t < 3; ++t) {
            const int n0 = 16 * (w2 * 3 + t);
            const float* wp = w_ih + (size_t)(n0 + arow) * kH + kgrp;
            #pragma unroll
            for (int kf = 0; kf < 4; ++kf)
                loadWFrag(wp + kf * 32, bfr[t * 4 + kf]);
        }
    }
    __syncthreads();

    // ---------------- phase 4: LayerNorm + ReLU (waves 0-7) ----------------
    if (wv < 8) {
        int r = wv;
        float v0 = hb[r * 128 + lane]      + fc_b[lane];
        float v1 = hb[r * 128 + lane + 64] + fc_b[lane + 64];
        float s  = waveReduceAdd(v0 + v1);
        float ss = waveReduceAdd(v0 * v0 + v1 * v1);
        float mu   = s * (1.0f / 128.0f);
        float var  = ss * (1.0f / 128.0f) - mu * mu;
        float rstd = rsqrtf(var + 1e-5f);
        float x0 = fmaxf((v0 - mu) * rstd * ln_g[lane] + ln_b[lane], 0.f);
        float x1 = fmaxf((v1 - mu) * rstd * ln_g[lane + 64] + ln_b[lane + 64], 0.f);
        xb16[r][lane]      = cvt1(x0);
        xb16[r][lane + 64] = cvt1(x1);
    }
    __syncthreads();

    // ---------------- phase 5: gi MFMA (waves 8-15)  ||  out_w preload (waves 0-3) ----------------
    Frag obf[4];     // held by waves 0-3
    if (wv >= 8) {
        const int w2 = wv - 8;
        Frag af[4];
        #pragma unroll
        for (int kf = 0; kf < 4; ++kf)
            *(uint4*)af[kf].u = *(const uint4*)&xb16[arow][kf * 32 + kgrp];
        #pragma unroll
        for (int t = 0; t < 3; ++t) {
            const int n0 = 16 * (w2 * 3 + t);
            f32x4 acc = {0.f, 0.f, 0.f, 0.f};
            #pragma unroll
            for (int kf = 0; kf < 4; ++kf)
                acc = __builtin_amdgcn_mfma_f32_16x16x32_bf16(af[kf].v, bfr[t * 4 + kf].v, acc, 0, 0, 0);
            #pragma unroll
            for (int j = 0; j < 4; ++j) {
                int row = (lane >> 4) * 4 + j;
                if (row < 8) gib[row][n0 + arow] = cvt1(acc[j]);
            }
        }
    } else if (wv < 4) {
        const int n0 = 16 * wv;                       // out head tile (0..64)
        const float* wp = out_w + (size_t)(n0 + arow) * kH + kgrp;
        #pragma unroll
        for (int kf = 0; kf < 4; ++kf)
            loadWFrag(wp + kf * 32, obf[kf]);
    }
    __syncthreads();

    // ---------------- phase 6: gate combine (all 1024 threads) ----------------
    {
        const int r = tid >> 7, fcol = tid & 127;
        float ir  = b2f(gib[r][fcol])       + b_ih[fcol];
        float iz  = b2f(gib[r][128 + fcol]) + b_ih[128 + fcol];
        float inn = b2f(gib[r][256 + fcol]) + b_ih[256 + fcol];
        float hr  = b2f(ghb[r][fcol])       + b_hh[fcol];
        float hz  = b2f(ghb[r][128 + fcol]) + b_hh[128 + fcol];
        float hn  = b2f(ghb[r][256 + fcol]) + b_hh[256 + fcol];
        float rg = 1.0f / (1.0f + __expf(-(ir + hr)));
        float zg = 1.0f / (1.0f + __expf(-(iz + hz)));
        float ng = tanhf(inn + rg * hn);
        float hprev = hf32[r * 128 + fcol];
        float hnew = (1.0f - zg) * ng + zg * hprev;
        hnb16[r][fcol] = cvt1(hnew);
        out[kOut0 + ((size_t)(b * kN + row0 + r)) * kH + fcol] = hnew;
    }
    __syncthreads();

    // ---------------- phase 7: out head (waves 0-3) ----------------
    if (wv < 4) {
        const int n0 = 16 * wv;
        Frag af[4];
        #pragma unroll
        for (int kf = 0; kf < 4; ++kf)
            *(uint4*)af[kf].u = *(const uint4*)&hnb16[arow][kf * 32 + kgrp];
        f32x4 acc = {0.f, 0.f, 0.f, 0.f};
        #pragma unroll
        for (int kf = 0; kf < 4; ++kf)
            acc = __builtin_amdgcn_mfma_f32_16x16x32_bf16(af[kf].v, obf[kf].v, acc, 0, 0, 0);
        float ob = out_b[n0 + arow];
        #pragma unroll
        for (int j = 0; j < 4; ++j) {
            int row = (lane >> 4) * 4 + j;
            if (row < 8)
                out[((size_t)(b * kN + row0 + row)) * kO + n0 + arow] = acc[j] + ob;
        }
    }
}

} // namespace

extern "C" void kernel_launch(void* const* d_in, const int* in_sizes, int n_in,
                              void* d_out, int out_size, void* d_ws, size_t ws_size,
                              hipStream_t stream) {
    const float* lx      = (const float*)d_in[0];
    const float* gx      = (const float*)d_in[1];
    const float* mask    = (const float*)d_in[2];
    const int*   key_idx = (const int*)  d_in[3];
    const float* hs      = (const float*)d_in[4];
    const float* fc_w    = (const float*)d_in[5];
    const float* fc_b    = (const float*)d_in[6];
    const float* ln_g    = (const float*)d_in[7];
    const float* ln_b    = (const float*)d_in[8];
    const float* w_ih    = (const float*)d_in[9];
    const float* w_hh    = (const float*)d_in[10];
    const float* b_ih    = (const float*)d_in[11];
    const float* b_hh    = (const float*)d_in[12];
    const float* out_w   = (const float*)d_in[13];
    const float* out_b   = (const float*)d_in[14];
    float* out = (float*)d_out;

    dim3 grid(kB * kN / kR);   // 256 blocks, 1 per CU
    dim3 block(kTPB);          // 1024 threads = 16 waves
    hipLaunchKernelGGL(weak_tie_fused, grid, block, 0, stream,
                       lx, gx, mask, key_idx, hs,
                       fc_w, fc_b, ln_g, ln_b,
                       w_ih, w_hh, b_ih, b_hh,
                       out_w, out_b, out);
}

// Round 5
// 19.316 us; speedup vs baseline: 2.9820x; 1.4210x over previous
//
#include <hip/hip_runtime.h>

namespace {

typedef unsigned short ushort_t;
typedef unsigned int uint_t;
typedef __attribute__((ext_vector_type(8))) short short8v;   // 8 bf16 (4 VGPRs)
typedef __attribute__((ext_vector_type(4))) float f32x4;     // MFMA accumulator

constexpr int kB = 8, kN = 256, kF = 128, kH = 128, kO = 64;
constexpr int kR = 8;              // real rows per block (padded to 16 for MFMA)
constexpr int kTPB = 1024;         // 16 waves
constexpr int kOut0 = kB * kN * kO;

// d_ws frag-slot bases (each slot = 64 lanes x 16B = 1KB, holds one B-frag set)
constexpr int FW_WHH  = 0;     // w_hh : 24 tiles x 4 kf  = 96
constexpr int FW_FCW  = 96;    // fc_w :  8 tiles x 12 kf = 96
constexpr int FW_WIH  = 192;   // w_ih : 24 tiles x 4 kf  = 96
constexpr int FW_OUTW = 288;   // out_w:  4 tiles x 4 kf  = 16
constexpr int FW_GX   = 304;   // gx   :  8 b x 8 tiles x 8 kf = 512
constexpr int FW_TOTAL = 816;  // 816 KB total in d_ws

union Frag {
    uint_t  u[4];
    short8v v;
};

__device__ __forceinline__ float waveReduceAdd(float v) {
    v += __shfl_xor(v, 1);
    v += __shfl_xor(v, 2);
    v += __shfl_xor(v, 4);
    v += __shfl_xor(v, 8);
    v += __shfl_xor(v, 16);
    v += __shfl_xor(v, 32);
    return v;
}

__device__ __forceinline__ ushort_t cvt1(float f) {
    return (ushort_t)((__float_as_uint(f) + 0x8000u) >> 16);
}
__device__ __forceinline__ uint_t pk(float f0, float f1) {
    uint_t b0 = __float_as_uint(f0) + 0x8000u;
    uint_t b1 = __float_as_uint(f1) + 0x8000u;
    return (b1 & 0xFFFF0000u) | (b0 >> 16);
}
__device__ __forceinline__ float b2f(ushort_t h) {
    return __uint_as_float(((uint_t)h) << 16);
}
__device__ __forceinline__ void loadWFrag(const float* __restrict__ p, Frag& b) {
    float4 lo = *(const float4*)p;
    float4 hi = *(const float4*)(p + 4);
    b.u[0] = pk(lo.x, lo.y);
    b.u[1] = pk(lo.z, lo.w);
    b.u[2] = pk(hi.x, hi.y);
    b.u[3] = pk(hi.z, hi.w);
}

// ---------------- pre-pass: build bf16 B-frags in d_ws ----------------
__global__ __launch_bounds__(256) void convert_frags(
    const float* __restrict__ gx, const float* __restrict__ fc_w,
    const float* __restrict__ w_ih, const float* __restrict__ w_hh,
    const float* __restrict__ out_w, uint4* __restrict__ ws)
{
    const int gw = (int)((blockIdx.x * 256 + threadIdx.x) >> 6);
    if (gw >= FW_TOTAL) return;
    const int lane = threadIdx.x & 63;
    const int arow = lane & 15;
    const int kgrp = (lane >> 4) * 8;
    Frag fr;
    if (gw < FW_FCW) {                       // w_hh
        int idx = gw - FW_WHH, t = idx >> 2, kf = idx & 3;
        loadWFrag(w_hh + (size_t)(t * 16 + arow) * kH + kf * 32 + kgrp, fr);
    } else if (gw < FW_WIH) {                // fc_w
        int idx = gw - FW_FCW, t = idx / 12, kf = idx % 12;
        loadWFrag(fc_w + (size_t)(t * 16 + arow) * 384 + kf * 32 + kgrp, fr);
    } else if (gw < FW_OUTW) {               // w_ih
        int idx = gw - FW_WIH, t = idx >> 2, kf = idx & 3;
        loadWFrag(w_ih + (size_t)(t * 16 + arow) * kH + kf * 32 + kgrp, fr);
    } else if (gw < FW_GX) {                 // out_w
        int idx = gw - FW_OUTW, t = idx >> 2, kf = idx & 3;
        loadWFrag(out_w + (size_t)(t * 16 + arow) * kH + kf * 32 + kgrp, fr);
    } else {                                 // gx weak-phase B-frags
        int idx = gw - FW_GX;
        int bb = idx >> 6, rem = idx & 63, t = rem >> 3, kf = rem & 7;
        int k0 = kf * 32 + kgrp;
        const float* gp = gx + ((size_t)bb * kN + k0) * kF + t * 16 + arow;
        fr.u[0] = pk(gp[0 * kF], gp[1 * kF]);
        fr.u[1] = pk(gp[2 * kF], gp[3 * kF]);
        fr.u[2] = pk(gp[4 * kF], gp[5 * kF]);
        fr.u[3] = pk(gp[6 * kF], gp[7 * kF]);
    }
    ws[(size_t)gw * 64 + lane] = *(uint4*)fr.u;
}

// ---------------- fused main kernel ----------------
__global__ __launch_bounds__(kTPB, 4) void weak_tie_fused(
    const float* __restrict__ lx, const float* __restrict__ gx,
    const float* __restrict__ mask, const int* __restrict__ key_idx,
    const float* __restrict__ hstate,
    const float* __restrict__ fc_b,
    const float* __restrict__ ln_g, const float* __restrict__ ln_b,
    const float* __restrict__ b_ih, const float* __restrict__ b_hh,
    const float* __restrict__ out_b,
    const uint4* __restrict__ ws,
    float* __restrict__ out)
{
    __shared__ __align__(16) ushort_t maskb[16][264];
    __shared__ __align__(16) ushort_t cmb[16][392];
    __shared__ __align__(16) ushort_t hf16[16][136];
    __shared__ __align__(16) ushort_t xb16[16][136];
    __shared__ __align__(16) ushort_t hnb16[16][136];
    __shared__ __align__(16) float hf32[kR * kH];
    __shared__ __align__(16) float hb[kR * kH];
    __shared__ __align__(16) ushort_t ghb[kR][384];
    __shared__ __align__(16) ushort_t gib[kR][384];
    __shared__ float denomInv[kR];

    const int tid  = threadIdx.x;
    const int b    = blockIdx.x >> 5;
    const int row0 = (blockIdx.x & 31) * kR;
    const int lane = tid & 63;
    const int wv   = tid >> 6;            // 0..15
    const int arow = lane & 15;
    const int kgrp = (lane >> 4) * 8;

    // ---------------- staging + zero pads ----------------
    {
        const int r = tid >> 7, c = tid & 127;
        const float* mrow = mask + ((size_t)b * kN + row0) * kN;
        maskb[r][c]       = cvt1(mrow[r * 256 + c]);
        maskb[r][c + 128] = cvt1(mrow[r * 256 + c + 128]);
        const float* lrow = lx + ((size_t)b * kN + row0) * kF;
        cmb[r][c] = cvt1(lrow[tid]);
        const int ki = key_idx[b];
        cmb[r][256 + c] = cvt1(gx[((size_t)b * kN + ki) * kF + c]);
        const float* hrow = hstate + ((size_t)b * kN + row0) * kH;
        float hv = hrow[tid];
        hf32[tid] = hv;
        hf16[r][c] = cvt1(hv);
        uint_t* z;
        z = (uint_t*)&maskb[8][0]; for (int i = tid; i < 8 * 264 / 2; i += kTPB) z[i] = 0;
        z = (uint_t*)&cmb[8][0];   for (int i = tid; i < 8 * 392 / 2; i += kTPB) z[i] = 0;
        z = (uint_t*)&hf16[8][0];  for (int i = tid; i < 8 * 136 / 2; i += kTPB) z[i] = 0;
        z = (uint_t*)&xb16[8][0];  for (int i = tid; i < 8 * 136 / 2; i += kTPB) z[i] = 0;
        z = (uint_t*)&hnb16[8][0]; for (int i = tid; i < 8 * 136 / 2; i += kTPB) z[i] = 0;
    }
    __syncthreads();

    // ---------------- denom (waves 0..7) ----------------
    if (wv < 8) {
        int r = wv;
        float s = b2f(maskb[r][lane])       + b2f(maskb[r][lane + 64]) +
                  b2f(maskb[r][lane + 128]) + b2f(maskb[r][lane + 192]);
        s = waveReduceAdd(s);
        if (lane == 0) denomInv[r] = 1.0f / (s + 1e-6f);
    }
    __syncthreads();

    // ---------------- P1: weak (waves 0-7) || gh (waves 8-15) ----------------
    if (wv < 8) {
        const uint4* wsf = ws + ((size_t)(FW_GX + b * 64 + wv * 8) * 64 + lane);
        f32x4 acc = {0.f, 0.f, 0.f, 0.f};
        #pragma unroll
        for (int kf = 0; kf < 8; ++kf) {
            Frag a, bb;
            *(uint4*)a.u  = *(const uint4*)&maskb[arow][kf * 32 + kgrp];
            *(uint4*)bb.u = wsf[(size_t)kf * 64];
            acc = __builtin_amdgcn_mfma_f32_16x16x32_bf16(a.v, bb.v, acc, 0, 0, 0);
        }
        const int n0 = 16 * wv;
        #pragma unroll
        for (int j = 0; j < 4; ++j) {
            int row = (lane >> 4) * 4 + j;
            if (row < 8)
                cmb[row][128 + n0 + arow] = cvt1(acc[j] * denomInv[row]);
        }
    } else {
        const int w2 = wv - 8;
        Frag af[4];
        #pragma unroll
        for (int kf = 0; kf < 4; ++kf)
            *(uint4*)af[kf].u = *(const uint4*)&hf16[arow][kf * 32 + kgrp];
        #pragma unroll
        for (int t = 0; t < 3; ++t) {
            const int tile = w2 * 3 + t;
            const uint4* wsf = ws + ((size_t)(FW_WHH + tile * 4) * 64 + lane);
            f32x4 acc = {0.f, 0.f, 0.f, 0.f};
            #pragma unroll
            for (int kf = 0; kf < 4; ++kf) {
                Frag bb;
                *(uint4*)bb.u = wsf[(size_t)kf * 64];
                acc = __builtin_amdgcn_mfma_f32_16x16x32_bf16(af[kf].v, bb.v, acc, 0, 0, 0);
            }
            const int n0 = 16 * tile;
            #pragma unroll
            for (int j = 0; j < 4; ++j) {
                int row = (lane >> 4) * 4 + j;
                if (row < 8) ghb[row][n0 + arow] = cvt1(acc[j]);
            }
        }
    }
    __syncthreads();

    // ---------------- P2: FC (waves 0-7) || gi weight preload (waves 8-15) ----------------
    Frag bfr[12];
    if (wv < 8) {
        const uint4* wsf = ws + ((size_t)(FW_FCW + wv * 12) * 64 + lane);
        f32x4 acc = {0.f, 0.f, 0.f, 0.f};
        #pragma unroll
        for (int kf = 0; kf < 12; ++kf) {
            Frag a, bb;
            *(uint4*)a.u  = *(const uint4*)&cmb[arow][kf * 32 + kgrp];
            *(uint4*)bb.u = wsf[(size_t)kf * 64];
            acc = __builtin_amdgcn_mfma_f32_16x16x32_bf16(a.v, bb.v, acc, 0, 0, 0);
        }
        const int n0 = 16 * wv;
        #pragma unroll
        for (int j = 0; j < 4; ++j) {
            int row = (lane >> 4) * 4 + j;
            if (row < 8) hb[row * 128 + n0 + arow] = acc[j];
        }
    } else {
        const int w2 = wv - 8;
        #pragma unroll
        for (int t = 0; t < 3; ++t) {
            const int tile = w2 * 3 + t;
            const uint4* wsf = ws + ((size_t)(FW_WIH + tile * 4) * 64 + lane);
            #pragma unroll
            for (int kf = 0; kf < 4; ++kf)
                *(uint4*)bfr[t * 4 + kf].u = wsf[(size_t)kf * 64];
        }
    }
    __syncthreads();

    // ---------------- P3: LayerNorm + ReLU (waves 0-7) ----------------
    if (wv < 8) {
        int r = wv;
        float v0 = hb[r * 128 + lane]      + fc_b[lane];
        float v1 = hb[r * 128 + lane + 64] + fc_b[lane + 64];
        float s  = waveReduceAdd(v0 + v1);
        float ss = waveReduceAdd(v0 * v0 + v1 * v1);
        float mu   = s * (1.0f / 128.0f);
        float var  = ss * (1.0f / 128.0f) - mu * mu;
        float rstd = rsqrtf(var + 1e-5f);
        float x0 = fmaxf((v0 - mu) * rstd * ln_g[lane] + ln_b[lane], 0.f);
        float x1 = fmaxf((v1 - mu) * rstd * ln_g[lane + 64] + ln_b[lane + 64], 0.f);
        xb16[r][lane]      = cvt1(x0);
        xb16[r][lane + 64] = cvt1(x1);
    }
    __syncthreads();

    // ---------------- P4: gi MFMA (waves 8-15) || out_w preload (waves 0-3) ----------------
    Frag obf[4];
    if (wv >= 8) {
        const int w2 = wv - 8;
        Frag af[4];
        #pragma unroll
        for (int kf = 0; kf < 4; ++kf)
            *(uint4*)af[kf].u = *(const uint4*)&xb16[arow][kf * 32 + kgrp];
        #pragma unroll
        for (int t = 0; t < 3; ++t) {
            const int n0 = 16 * (w2 * 3 + t);
            f32x4 acc = {0.f, 0.f, 0.f, 0.f};
            #pragma unroll
            for (int kf = 0; kf < 4; ++kf)
                acc = __builtin_amdgcn_mfma_f32_16x16x32_bf16(af[kf].v, bfr[t * 4 + kf].v, acc, 0, 0, 0);
            #pragma unroll
            for (int j = 0; j < 4; ++j) {
                int row = (lane >> 4) * 4 + j;
                if (row < 8) gib[row][n0 + arow] = cvt1(acc[j]);
            }
        }
    } else if (wv < 4) {
        const uint4* wsf = ws + ((size_t)(FW_OUTW + wv * 4) * 64 + lane);
        #pragma unroll
        for (int kf = 0; kf < 4; ++kf)
            *(uint4*)obf[kf].u = wsf[(size_t)kf * 64];
    }
    __syncthreads();

    // ---------------- P5: gate combine (all 1024 threads) ----------------
    {
        const int r = tid >> 7, fcol = tid & 127;
        float ir  = b2f(gib[r][fcol])       + b_ih[fcol];
        float iz  = b2f(gib[r][128 + fcol]) + b_ih[128 + fcol];
        float inn = b2f(gib[r][256 + fcol]) + b_ih[256 + fcol];
        float hr  = b2f(ghb[r][fcol])       + b_hh[fcol];
        float hz  = b2f(ghb[r][128 + fcol]) + b_hh[128 + fcol];
        float hn  = b2f(ghb[r][256 + fcol]) + b_hh[256 + fcol];
        float rg = 1.0f / (1.0f + __expf(-(ir + hr)));
        float zg = 1.0f / (1.0f + __expf(-(iz + hz)));
        float ng = tanhf(inn + rg * hn);
        float hprev = hf32[r * 128 + fcol];
        float hnew = (1.0f - zg) * ng + zg * hprev;
        hnb16[r][fcol] = cvt1(hnew);
        out[kOut0 + ((size_t)(b * kN + row0 + r)) * kH + fcol] = hnew;
    }
    __syncthreads();

    // ---------------- P6: out head (waves 0-3) ----------------
    if (wv < 4) {
        const int n0 = 16 * wv;
        Frag af[4];
        #pragma unroll
        for (int kf = 0; kf < 4; ++kf)
            *(uint4*)af[kf].u = *(const uint4*)&hnb16[arow][kf * 32 + kgrp];
        f32x4 acc = {0.f, 0.f, 0.f, 0.f};
        #pragma unroll
        for (int kf = 0; kf < 4; ++kf)
            acc = __builtin_amdgcn_mfma_f32_16x16x32_bf16(af[kf].v, obf[kf].v, acc, 0, 0, 0);
        float ob = out_b[n0 + arow];
        #pragma unroll
        for (int j = 0; j < 4; ++j) {
            int row = (lane >> 4) * 4 + j;
            if (row < 8)
                out[((size_t)(b * kN + row0 + row)) * kO + n0 + arow] = acc[j] + ob;
        }
    }
}

} // namespace

extern "C" void kernel_launch(void* const* d_in, const int* in_sizes, int n_in,
                              void* d_out, int out_size, void* d_ws, size_t ws_size,
                              hipStream_t stream) {
    const float* lx      = (const float*)d_in[0];
    const float* gx      = (const float*)d_in[1];
    const float* mask    = (const float*)d_in[2];
    const int*   key_idx = (const int*)  d_in[3];
    const float* hs      = (const float*)d_in[4];
    const float* fc_w    = (const float*)d_in[5];
    const float* fc_b    = (const float*)d_in[6];
    const float* ln_g    = (const float*)d_in[7];
    const float* ln_b    = (const float*)d_in[8];
    const float* w_ih    = (const float*)d_in[9];
    const float* w_hh    = (const float*)d_in[10];
    const float* b_ih    = (const float*)d_in[11];
    const float* b_hh    = (const float*)d_in[12];
    const float* out_w   = (const float*)d_in[13];
    const float* out_b   = (const float*)d_in[14];
    float* out = (float*)d_out;
    uint4* ws = (uint4*)d_ws;   // needs 816 KB

    // pre-pass: 816 frag-waves * 64 lanes = 52224 threads
    hipLaunchKernelGGL(convert_frags, dim3((FW_TOTAL * 64) / 256), dim3(256), 0, stream,
                       gx, fc_w, w_ih, w_hh, out_w, ws);

    dim3 grid(kB * kN / kR);   // 256 blocks
    dim3 block(kTPB);          // 1024 threads
    hipLaunchKernelGGL(weak_tie_fused, grid, block, 0, stream,
                       lx, gx, mask, key_idx, hs,
                       fc_b, ln_g, ln_b,
                       b_ih, b_hh, out_b,
                       (const uint4*)ws, out);
}